// Round 11
// baseline (174.728 us; speedup 1.0000x reference)
//
#include <hip/hip_runtime.h>
#include <stdint.h>

// HMM trajectory-net forward:  -logsumexp over an 8191-step 64-state HMM scan.
// Pipeline:
//   conv_*       : fp32 -> bf16 repacks
//   small_gemm   : start/stop logits via MFMA, fused softmax/sigmoid -> ps, pb, pc
//   act_gemm     : B-group in VGPRs (no LDS, no barriers), 8 t-subtiles per block,
//                  fused no-max softmax + action-select -> peT[b][t]
//   chunk_kernel : 128 chunks x 64 steps; 4 waves/chunk, 64x64 transfer matrix in
//                  registers; scalars staged in LDS (2-pass for peT layout)
//   group_combine: 16 blocks x 7 matmuls, LDS-resident operands, double-buffered
//                  global->LDS prefetch of the next matrix (latency hidden)
//   final_combine: 16 sequential mat-vecs (4-wave split) + boundary terms -> scalar

typedef short bf16x8 __attribute__((ext_vector_type(8)));
typedef float f32x4  __attribute__((ext_vector_type(4)));
typedef unsigned short u16;

#define T_LEN 8192
#define SDIM  256

// ---- workspace layout (bytes) ----
#define WS_SBF    0              // 8256*256 bf16 (padded rows zeroed)
#define WS_WAT    4227072        // 4096*256 bf16  [b*64+n][s]
#define WS_WSMT   6324224        // 192*256 bf16   [col][s]
#define WS_PE     6422528        // peT: 64*8192 f32  [b][t]
#define WS_PS     8519680        // 8193*64 f32
#define WS_PB     10617088       // 8193*64 f32
#define WS_PC     12714496       // 8193*64 f32   (dead after chunk_kernel -> reused for Gout)
#define WS_MOUT   14811904       // 128*4096 f32  [chunk][k][j]
#define WS_LSC    16909056       // 128 f32
#define WS_GOUT   WS_PC                      // 16*4096 f32 (reuses pc region)
#define WS_GLSC   (WS_PC + 262144)           // 16 f32

__device__ inline u16 f2bf(float f) {
  union { float f; uint32_t u; } v; v.f = f;
  uint32_t u = v.u;
  return (u16)((u + 0x7fffu + ((u >> 16) & 1u)) >> 16);
}

// ---------------- converts ----------------
__global__ void conv_s(const float* __restrict__ s_i, u16* __restrict__ s_bf) {
  int idx = blockIdx.x * 256 + threadIdx.x;
  int t = idx >> 8;
  float v = (t < T_LEN + 1) ? s_i[idx] : 0.f;
  s_bf[idx] = f2bf(v);
}

__global__ void conv_wa(const float* __restrict__ Wa, u16* __restrict__ wa_t) {
  int idx = blockIdx.x * 256 + threadIdx.x;
  int s = idx >> 12, bn = idx & 4095;
  wa_t[bn * 256 + s] = f2bf(Wa[idx]);
}

__global__ void conv_wsm(const float* __restrict__ Wstop, const float* __restrict__ Wstart,
                         u16* __restrict__ wsm_t) {
  int idx = blockIdx.x * 256 + threadIdx.x;
  int col = idx >> 8, s = idx & 255;
  float v;
  if (col < 64)       v = Wstart[s * 64 + col];
  else if (col < 128) v = Wstop[s * 128 + (col - 64) * 2 + 0];
  else                v = Wstop[s * 128 + (col - 128) * 2 + 1];
  wsm_t[col * 256 + s] = f2bf(v);
}

// ---------------- action GEMM + fused emit ----------------
// Grid: 512 blocks = 8 t-slabs x 64 b-groups; slab = bid & 7 -> one slab per XCD
// (A-slab 512 KB stays L2-resident; B 64x32KB = 2 MB per XCD).
// Block: 512 threads = 8 waves; wave owns 16 t-rows per iter, 8 iters (1024 t).
// B-group (64x256 bf16) loaded ONCE into VGPRs (32 frags = 128 VGPR); steady
// state has NO LDS traffic and NO barriers: {A-loads -> 32 MFMA -> epilogue}.
// Epilogue: no-max softmax (logits ~N(0,0.32^2)), pe = exp(v_sel)/sum(exp),
// transposed store peT[b][t].
__global__ __launch_bounds__(512, 2) void act_gemm(
    const u16* __restrict__ s_bf, const u16* __restrict__ wa_t,
    const int* __restrict__ actions, float* __restrict__ peT) {
  const int tid = threadIdx.x;
  const int lane = tid & 63;
  const int wmv = tid >> 6;            // 0..7
  const int g = lane >> 4, c = lane & 15;

  const int bid = blockIdx.x;
  const int slab = bid & 7;            // t-slab (XCD-local)
  const int b0 = bid >> 3;             // b-group

  // B-group into VGPRs: bq[ks][nf], lane holds row nf*16+c, cols ks*32+g*8
  bf16x8 bq[8][4];
  {
    const u16* bbase = wa_t + (size_t)b0 * 64 * 256 + (size_t)c * 256 + g * 8;
#pragma unroll
    for (int ks = 0; ks < 8; ++ks)
#pragma unroll
      for (int nf = 0; nf < 4; ++nf)
        bq[ks][nf] = *(const bf16x8*)(bbase + nf * 16 * 256 + ks * 32);
  }

  const size_t pebase = (size_t)b0 * 8192;

  for (int it = 0; it < 8; ++it) {
    const int tbase = slab * 1024 + it * 128 + wmv * 16;

    // A fragments: lane holds t-row tbase+c, cols ks*32+g*8
    const u16* arow = s_bf + (size_t)(tbase + c) * 256 + g * 8;
    bf16x8 af[8];
#pragma unroll
    for (int ks = 0; ks < 8; ++ks)
      af[ks] = *(const bf16x8*)(arow + ks * 32);

    int a0 = actions[tbase + g * 4 + 0];
    int a1 = actions[tbase + g * 4 + 1];
    int a2 = actions[tbase + g * 4 + 2];
    int a3 = actions[tbase + g * 4 + 3];

    f32x4 acc[4];
#pragma unroll
    for (int nf = 0; nf < 4; ++nf) acc[nf] = (f32x4){0.f, 0.f, 0.f, 0.f};

#pragma unroll
    for (int ks = 0; ks < 8; ++ks)
#pragma unroll
      for (int nf = 0; nf < 4; ++nf)
        acc[nf] = __builtin_amdgcn_mfma_f32_16x16x32_bf16(af[ks], bq[ks][nf], acc[nf], 0, 0, 0);

    // epilogue: row g*4+q; no-max softmax over 64 cols (16 c-lanes x 4 nf)
    const int acts[4] = {a0, a1, a2, a3};
#pragma unroll
    for (int q = 0; q < 4; ++q) {
      float e0 = __expf(acc[0][q]);
      float e1 = __expf(acc[1][q]);
      float e2 = __expf(acc[2][q]);
      float e3 = __expf(acc[3][q]);
      float s = (e0 + e1) + (e2 + e3);
#pragma unroll
      for (int d = 1; d < 16; d <<= 1) s += __shfl_xor(s, d);
      int a = acts[q];
      int acf = a >> 4;
      float esel = (acf == 0) ? e0 : (acf == 1) ? e1 : (acf == 2) ? e2 : e3;
      if (c == (a & 15))
        peT[pebase + tbase + g * 4 + q] = esel / s;
    }
  }
}

// ---------------- start/stop GEMM + fused softmax/sigmoid ----------------
__global__ __launch_bounds__(256) void small_gemm(
    const u16* __restrict__ s_bf, const u16* __restrict__ wsm_t,
    float* __restrict__ ps, float* __restrict__ pb, float* __restrict__ pc) {
  __shared__ uint4 ldsA[64 * 16];
  __shared__ uint4 ldsB[192 * 16];
  const int t0 = blockIdx.x * 64;
  const int tid = threadIdx.x;
  const int lane = tid & 63, w = tid >> 6;
  const int g = lane >> 4, c = lane & 15;

  f32x4 acc[12];
#pragma unroll
  for (int i = 0; i < 12; ++i) acc[i] = (f32x4){0.f, 0.f, 0.f, 0.f};

  for (int kh = 0; kh < 2; ++kh) {
    if (kh) __syncthreads();
    for (int i = tid; i < 64 * 16; i += 256) {
      int row = i >> 4, u = i & 15;
      ldsA[(row * 16 + u) ^ (row & 7)] =
          *(const uint4*)(s_bf + (size_t)(t0 + row) * 256 + kh * 128 + u * 8);
    }
    for (int i = tid; i < 192 * 16; i += 256) {
      int row = i >> 4, u = i & 15;
      ldsB[(row * 16 + u) ^ (row & 7)] =
          *(const uint4*)(wsm_t + (size_t)row * 256 + kh * 128 + u * 8);
    }
    __syncthreads();
#pragma unroll
    for (int kk = 0; kk < 4; ++kk) {
      int u = kk * 4 + g;
      int arow = w * 16 + c;
      bf16x8 af = *(const bf16x8*)&ldsA[(arow * 16 + u) ^ (arow & 7)];
#pragma unroll
      for (int cf = 0; cf < 12; ++cf) {
        int brow = cf * 16 + c;
        bf16x8 bfr = *(const bf16x8*)&ldsB[(brow * 16 + u) ^ (brow & 7)];
        acc[cf] = __builtin_amdgcn_mfma_f32_16x16x32_bf16(af, bfr, acc[cf], 0, 0, 0);
      }
    }
  }

#pragma unroll
  for (int q = 0; q < 4; ++q) {
    int t = t0 + w * 16 + g * 4 + q;
    float v0 = acc[0][q], v1 = acc[1][q], v2 = acc[2][q], v3 = acc[3][q];
    float m = fmaxf(fmaxf(v0, v1), fmaxf(v2, v3));
#pragma unroll
    for (int d = 1; d < 16; d <<= 1) m = fmaxf(m, __shfl_xor(m, d));
    float s = __expf(v0 - m) + __expf(v1 - m) + __expf(v2 - m) + __expf(v3 - m);
#pragma unroll
    for (int d = 1; d < 16; d <<= 1) s += __shfl_xor(s, d);
    float lse = m + __logf(s);
    if (t <= T_LEN) {
      ps[t * 64 + 0 * 16 + c] = __expf(v0 - lse);
      ps[t * 64 + 1 * 16 + c] = __expf(v1 - lse);
      ps[t * 64 + 2 * 16 + c] = __expf(v2 - lse);
      ps[t * 64 + 3 * 16 + c] = __expf(v3 - lse);
#pragma unroll
      for (int bf = 0; bf < 4; ++bf) {
        float l0 = acc[4 + bf][q], l1 = acc[8 + bf][q];
        float d01 = l0 - l1;
        pb[t * 64 + bf * 16 + c] = 1.f / (1.f + __expf(-d01));
        pc[t * 64 + bf * 16 + c] = 1.f / (1.f + __expf(d01));
      }
    }
  }
}

// ---------------- chunked scan: 4 waves per chunk ----------------
__global__ __launch_bounds__(256) void chunk_kernel(
    const float* __restrict__ peT, const float* __restrict__ ps,
    const float* __restrict__ pb, const float* __restrict__ pc,
    float* __restrict__ Mout, float* __restrict__ lscale) {
  __shared__ float scal[64 * 196];   // per step: [b(64) | ec(64) | es(64) | pad]
  __shared__ float part[2][256];
  __shared__ float mxs[4];
  const int ck = blockIdx.x;
  const int tid = threadIdx.x;
  const int lane = tid & 63;
  const int w = tid >> 6;
  const int tlo = ck * 64 + 1;

#pragma unroll
  for (int it = 0; it < 16; ++it) {
    int i = tid + 256 * it;
    int st = i >> 6, j = i & 63;
    int t = tlo + st;
    if (t <= T_LEN - 1) {
      int base = t * 64 + j;
      scal[st * 196 + j]       = pb[base];
      scal[st * 196 + 64 + j]  = pc[base];
      scal[st * 196 + 128 + j] = ps[base];
    } else {
      scal[st * 196 + j]       = 0.f;
      scal[st * 196 + 64 + j]  = 1.f;
      scal[st * 196 + 128 + j] = 0.f;
    }
  }
  __syncthreads();
#pragma unroll
  for (int it = 0; it < 16; ++it) {
    int i = tid + 256 * it;
    int j = i >> 6, st = i & 63;
    int t = tlo + st;
    if (t <= T_LEN - 1) {
      float e = peT[(size_t)j * 8192 + t];
      scal[st * 196 + 64 + j]  *= e;
      scal[st * 196 + 128 + j] *= e;
    }
  }
  __syncthreads();

  float M[16];
#pragma unroll
  for (int jj = 0; jj < 16; ++jj) M[jj] = ((w * 16 + jj) == lane) ? 1.f : 0.f;
  float lsc = 0.f;
  int pbuf = 0;

  for (int st = 0; st < 64; ++st) {
    const float* sb = &scal[st * 196];
    float p0 = 0.f, p1 = 0.f, p2 = 0.f, p3 = 0.f;
#pragma unroll
    for (int q = 0; q < 4; ++q) {
      float4 bq = *(const float4*)(sb + w * 16 + q * 4);
      p0 = fmaf(bq.x, M[q * 4 + 0], p0);
      p1 = fmaf(bq.y, M[q * 4 + 1], p1);
      p2 = fmaf(bq.z, M[q * 4 + 2], p2);
      p3 = fmaf(bq.w, M[q * 4 + 3], p3);
    }
    part[pbuf][w * 64 + lane] = (p0 + p1) + (p2 + p3);
    __syncthreads();
    float wv = part[pbuf][lane] + part[pbuf][64 + lane] +
               part[pbuf][128 + lane] + part[pbuf][192 + lane];
    pbuf ^= 1;
#pragma unroll
    for (int q = 0; q < 4; ++q) {
      float4 ecq = *(const float4*)(sb + 64 + w * 16 + q * 4);
      float4 esq = *(const float4*)(sb + 128 + w * 16 + q * 4);
      M[q * 4 + 0] = fmaf(ecq.x, M[q * 4 + 0], esq.x * wv);
      M[q * 4 + 1] = fmaf(ecq.y, M[q * 4 + 1], esq.y * wv);
      M[q * 4 + 2] = fmaf(ecq.z, M[q * 4 + 2], esq.z * wv);
      M[q * 4 + 3] = fmaf(ecq.w, M[q * 4 + 3], esq.w * wv);
    }
    if ((st & 7) == 7) {
      float mx = M[0];
#pragma unroll
      for (int jj = 1; jj < 16; ++jj) mx = fmaxf(mx, M[jj]);
#pragma unroll
      for (int d = 1; d < 64; d <<= 1) mx = fmaxf(mx, __shfl_xor(mx, d));
      if (lane == 0) mxs[w] = mx;
      __syncthreads();
      float bm = fmaxf(fmaxf(mxs[0], mxs[1]), fmaxf(mxs[2], mxs[3]));
      float inv = 1.f / bm;
#pragma unroll
      for (int jj = 0; jj < 16; ++jj) M[jj] *= inv;
      lsc += __logf(bm);
    }
  }

  float* out = Mout + (size_t)ck * 4096;
#pragma unroll
  for (int q = 0; q < 4; ++q) {
    float4 v = make_float4(M[q * 4 + 0], M[q * 4 + 1], M[q * 4 + 2], M[q * 4 + 3]);
    *(float4*)(out + lane * 64 + w * 16 + q * 4) = v;
  }
  if (tid == 0) lscale[ck] = lsc;
}

// ---------------- level-1 combine: 16 groups x 8 chunk matrices ----------------
// LDS-resident operands + double-buffered prefetch of the next matrix.
__global__ __launch_bounds__(256) void group_combine(
    const float* __restrict__ Mout, const float* __restrict__ lscale,
    float* __restrict__ Gout, float* __restrict__ glsc) {
  const int g = blockIdx.x;
  const int tid = threadIdx.x;
  const int j = tid & 63;
  const int w = tid >> 6;
  __shared__ float Xa[64 * 68];
  __shared__ float Xb[64 * 68];
  __shared__ float Ma[64 * 68];
  __shared__ float Mb[64 * 68];
  __shared__ float red[4];

  {
    const float* M0 = Mout + (size_t)(8 * g) * 4096;
    const float* M1 = Mout + (size_t)(8 * g + 1) * 4096;
    for (int idx = tid; idx < 4096; idx += 256) {
      int i = idx >> 6, r = idx & 63;
      Xa[r * 68 + i] = M0[idx];
      Ma[i * 68 + r] = M1[idx];
    }
  }
  __syncthreads();

  float lsc = 0.f;
  float* Xcur = Xa; float* Xnxt = Xb;
  float* Mcur = Ma; float* Mnxt = Mb;

  for (int m = 1; m < 8; ++m) {
    float4 pf[4];
    if (m < 7) {
      const float* Mn = Mout + (size_t)(8 * g + m + 1) * 4096;
#pragma unroll
      for (int ii = 0; ii < 4; ++ii)
        pf[ii] = *(const float4*)(Mn + tid * 4 + 1024 * ii);
    }

    float acc[16];
#pragma unroll
    for (int i = 0; i < 16; ++i) acc[i] = 0.f;

#pragma unroll 4
    for (int k = 0; k < 64; ++k) {
      float mv = Mcur[k * 68 + j];
      const float* xr = Xcur + k * 68 + (w << 4);
      float4 x0 = *(const float4*)(xr + 0);
      float4 x1 = *(const float4*)(xr + 4);
      float4 x2 = *(const float4*)(xr + 8);
      float4 x3 = *(const float4*)(xr + 12);
      acc[0]  = fmaf(mv, x0.x, acc[0]);  acc[1]  = fmaf(mv, x0.y, acc[1]);
      acc[2]  = fmaf(mv, x0.z, acc[2]);  acc[3]  = fmaf(mv, x0.w, acc[3]);
      acc[4]  = fmaf(mv, x1.x, acc[4]);  acc[5]  = fmaf(mv, x1.y, acc[5]);
      acc[6]  = fmaf(mv, x1.z, acc[6]);  acc[7]  = fmaf(mv, x1.w, acc[7]);
      acc[8]  = fmaf(mv, x2.x, acc[8]);  acc[9]  = fmaf(mv, x2.y, acc[9]);
      acc[10] = fmaf(mv, x2.z, acc[10]); acc[11] = fmaf(mv, x2.w, acc[11]);
      acc[12] = fmaf(mv, x3.x, acc[12]); acc[13] = fmaf(mv, x3.y, acc[13]);
      acc[14] = fmaf(mv, x3.z, acc[14]); acc[15] = fmaf(mv, x3.w, acc[15]);
    }

    float lm = acc[0];
#pragma unroll
    for (int i = 1; i < 16; ++i) lm = fmaxf(lm, acc[i]);
#pragma unroll
    for (int d = 1; d < 64; d <<= 1) lm = fmaxf(lm, __shfl_xor(lm, d));
    if ((tid & 63) == 0) red[w] = lm;
    __syncthreads();
    float bm = fmaxf(fmaxf(red[0], red[1]), fmaxf(red[2], red[3]));
    float inv = 1.f / bm;
    lsc += __logf(bm);
#pragma unroll
    for (int i = 0; i < 16; ++i)
      Xnxt[j * 68 + (w << 4) + i] = acc[i] * inv;
    if (m < 7) {
#pragma unroll
      for (int ii = 0; ii < 4; ++ii) {
        int idx = tid * 4 + 1024 * ii;
        int k = idx >> 6, jj = idx & 63;
        *(float4*)(Mnxt + k * 68 + jj) = pf[ii];
      }
    }
    __syncthreads();
    float* t = Xcur; Xcur = Xnxt; Xnxt = t;
    float* tm = Mcur; Mcur = Mnxt; Mnxt = tm;
  }

  float* out = Gout + (size_t)g * 4096;
  for (int idx = tid; idx < 4096; idx += 256) {
    int i = idx >> 6, r = idx & 63;
    out[idx] = Xcur[r * 68 + i];
  }
  if (tid == 0) {
    float s = lsc;
#pragma unroll
    for (int m = 0; m < 8; ++m) s += lscale[8 * g + m];
    glsc[g] = s;
  }
}

// ---------------- level-2 combine: 16 sequential mat-vecs ----------------
__global__ __launch_bounds__(256) void final_combine(
    const float* __restrict__ Gout, const float* __restrict__ glsc,
    const float* __restrict__ peT, const float* __restrict__ ps,
    const float* __restrict__ pb, float* __restrict__ out) {
  const int tid = threadIdx.x;
  const int j = tid & 63, w = tid >> 6;
  __shared__ float vsh[64];
  __shared__ float part[4 * 64];
  if (tid < 64) vsh[tid] = ps[tid] * peT[(size_t)tid * 8192];   // f0
  __syncthreads();
  double lsc = 0.0;
  for (int gph = 0; gph < 16; ++gph) {
    const float* Gc = Gout + (size_t)gph * 4096;
    const int k0 = w << 4;
    float a0 = 0.f, a1 = 0.f, a2 = 0.f, a3 = 0.f;
#pragma unroll
    for (int kk = 0; kk < 16; kk += 4) {
      a0 = fmaf(vsh[k0 + kk + 0], Gc[(k0 + kk + 0) * 64 + j], a0);
      a1 = fmaf(vsh[k0 + kk + 1], Gc[(k0 + kk + 1) * 64 + j], a1);
      a2 = fmaf(vsh[k0 + kk + 2], Gc[(k0 + kk + 2) * 64 + j], a2);
      a3 = fmaf(vsh[k0 + kk + 3], Gc[(k0 + kk + 3) * 64 + j], a3);
    }
    part[w * 64 + j] = (a0 + a1) + (a2 + a3);
    __syncthreads();
    if (w == 0) {
      float u = part[j] + part[64 + j] + part[128 + j] + part[192 + j];
      float mx = u;
#pragma unroll
      for (int d = 1; d < 64; d <<= 1) mx = fmaxf(mx, __shfl_xor(mx, d));
      vsh[j] = u / mx;
      lsc += (double)__logf(mx) + (double)glsc[gph];
    }
    __syncthreads();
  }
  if (w == 0) {
    float z = vsh[j] * pb[T_LEN * 64 + j];
#pragma unroll
    for (int d = 1; d < 64; d <<= 1) z += __shfl_xor(z, d);
    if (j == 0) out[0] = (float)(-((double)logf(z) + lsc));
  }
}

extern "C" void kernel_launch(void* const* d_in, const int* in_sizes, int n_in,
                              void* d_out, int out_size, void* d_ws, size_t ws_size,
                              hipStream_t stream) {
  const float* s_i      = (const float*)d_in[0];
  const float* W_action = (const float*)d_in[1];
  const float* W_stop   = (const float*)d_in[2];
  const float* W_start  = (const float*)d_in[3];
  const int*   actions  = (const int*)d_in[4];

  char* ws = (char*)d_ws;
  u16*   s_bf  = (u16*)(ws + WS_SBF);
  u16*   wa_t  = (u16*)(ws + WS_WAT);
  u16*   wsm_t = (u16*)(ws + WS_WSMT);
  float* peT   = (float*)(ws + WS_PE);
  float* ps    = (float*)(ws + WS_PS);
  float* pb    = (float*)(ws + WS_PB);
  float* pc    = (float*)(ws + WS_PC);
  float* Mout  = (float*)(ws + WS_MOUT);
  float* lsc   = (float*)(ws + WS_LSC);
  float* Gout  = (float*)(ws + WS_GOUT);
  float* glsc  = (float*)(ws + WS_GLSC);

  conv_s<<<8256, 256, 0, stream>>>(s_i, s_bf);
  conv_wa<<<4096, 256, 0, stream>>>(W_action, wa_t);
  conv_wsm<<<192, 256, 0, stream>>>(W_stop, W_start, wsm_t);
  small_gemm<<<129, 256, 0, stream>>>(s_bf, wsm_t, ps, pb, pc);
  act_gemm<<<512, 512, 0, stream>>>(s_bf, wa_t, actions, peT);
  chunk_kernel<<<128, 256, 0, stream>>>(peT, ps, pb, pc, Mout, lsc);
  group_combine<<<16, 256, 0, stream>>>(Mout, lsc, Gout, glsc);
  final_combine<<<1, 256, 0, stream>>>(Gout, glsc, peT, ps, pb, (float*)d_out);
}

// Round 12
// 170.212 us; speedup vs baseline: 1.0265x; 1.0265x over previous
//
#include <hip/hip_runtime.h>
#include <stdint.h>

// HMM trajectory-net forward:  -logsumexp over an 8191-step 64-state HMM scan.
// Pipeline:
//   conv_*       : fp32 -> bf16 repacks
//   small_gemm   : start/stop logits via MFMA, fused softmax/sigmoid -> ps, pb, pc
//   act_gemm     : B-group pinned in VGPRs (asm keep-alive), no LDS/no barriers,
//                  8 t-subtiles per block with A prefetch, fused no-max softmax -> peT
//   chunk_kernel : 128 chunks x 64 steps; 4 waves/chunk, 64x64 transfer matrix in
//                  registers; scalars staged in LDS (2-pass for peT layout)
//   group_combine: 16 blocks x 7 matmuls, LDS-resident operands, double-buffered
//                  global->LDS prefetch of the next matrix (latency hidden)
//   final_combine: 16 sequential mat-vecs (4-wave split) + boundary terms -> scalar

typedef short bf16x8 __attribute__((ext_vector_type(8)));
typedef float f32x4  __attribute__((ext_vector_type(4)));
typedef unsigned short u16;

#define T_LEN 8192
#define SDIM  256

// ---- workspace layout (bytes) ----
#define WS_SBF    0              // 8256*256 bf16 (padded rows zeroed)
#define WS_WAT    4227072        // 4096*256 bf16  [b*64+n][s]
#define WS_WSMT   6324224        // 192*256 bf16   [col][s]
#define WS_PE     6422528        // peT: 64*8192 f32  [b][t]
#define WS_PS     8519680        // 8193*64 f32
#define WS_PB     10617088       // 8193*64 f32
#define WS_PC     12714496       // 8193*64 f32   (dead after chunk_kernel -> reused for Gout)
#define WS_MOUT   14811904       // 128*4096 f32  [chunk][k][j]
#define WS_LSC    16909056       // 128 f32
#define WS_GOUT   WS_PC                      // 16*4096 f32 (reuses pc region)
#define WS_GLSC   (WS_PC + 262144)           // 16 f32

__device__ inline u16 f2bf(float f) {
  union { float f; uint32_t u; } v; v.f = f;
  uint32_t u = v.u;
  return (u16)((u + 0x7fffu + ((u >> 16) & 1u)) >> 16);
}

// ---------------- converts ----------------
__global__ void conv_s(const float* __restrict__ s_i, u16* __restrict__ s_bf) {
  int idx = blockIdx.x * 256 + threadIdx.x;
  int t = idx >> 8;
  float v = (t < T_LEN + 1) ? s_i[idx] : 0.f;
  s_bf[idx] = f2bf(v);
}

__global__ void conv_wa(const float* __restrict__ Wa, u16* __restrict__ wa_t) {
  int idx = blockIdx.x * 256 + threadIdx.x;
  int s = idx >> 12, bn = idx & 4095;
  wa_t[bn * 256 + s] = f2bf(Wa[idx]);
}

__global__ void conv_wsm(const float* __restrict__ Wstop, const float* __restrict__ Wstart,
                         u16* __restrict__ wsm_t) {
  int idx = blockIdx.x * 256 + threadIdx.x;
  int col = idx >> 8, s = idx & 255;
  float v;
  if (col < 64)       v = Wstart[s * 64 + col];
  else if (col < 128) v = Wstop[s * 128 + (col - 64) * 2 + 0];
  else                v = Wstop[s * 128 + (col - 128) * 2 + 1];
  wsm_t[col * 256 + s] = f2bf(v);
}

// ---------------- action GEMM + fused emit ----------------
// Grid: 512 blocks = 8 t-slabs x 64 b-groups; slab = bid & 7 -> one slab per XCD.
// Block: 512 threads = 8 waves; wave owns 16 t-rows per iter, 8 iters (1024 t).
// B-group (64x256 bf16) loaded ONCE into VGPRs (32 frags = 128 VGPR) and PINNED
// with an opaque asm def so the compiler cannot rematerialize the loads.
// Steady state: {A-prefetch(next) -> 32 MFMA -> epilogue}, no LDS, no barriers.
// Epilogue: no-max softmax (logits ~N(0,0.32^2)), pe = exp(v_sel)/sum(exp),
// transposed store peT[b][t].
__global__ __launch_bounds__(512, 2) void act_gemm(
    const u16* __restrict__ s_bf, const u16* __restrict__ wa_t,
    const int* __restrict__ actions, float* __restrict__ peT) {
  const int tid = threadIdx.x;
  const int lane = tid & 63;
  const int wmv = tid >> 6;            // 0..7
  const int g = lane >> 4, c = lane & 15;

  const int bid = blockIdx.x;
  const int slab = bid & 7;            // t-slab (XCD-local)
  const int b0 = bid >> 3;             // b-group

  // B-group into VGPRs: bq[ks][nf], lane holds row nf*16+c, cols ks*32+g*8
  bf16x8 bq[8][4];
  {
    const u16* bbase = wa_t + (size_t)b0 * 64 * 256 + (size_t)c * 256 + g * 8;
#pragma unroll
    for (int ks = 0; ks < 8; ++ks)
#pragma unroll
      for (int nf = 0; nf < 4; ++nf) {
        bq[ks][nf] = *(const bf16x8*)(bbase + nf * 16 * 256 + ks * 32);
        asm volatile("" : "+v"(bq[ks][nf]));   // pin: opaque def, no remat
      }
  }

  const size_t pebase = (size_t)b0 * 8192;
  const int tw = slab * 1024 + wmv * 16;

  // prefetch A for iter 0
  bf16x8 af[8], afn[8];
  {
    const u16* arow = s_bf + (size_t)(tw + c) * 256 + g * 8;
#pragma unroll
    for (int ks = 0; ks < 8; ++ks) af[ks] = *(const bf16x8*)(arow + ks * 32);
  }

#pragma unroll 1
  for (int it = 0; it < 8; ++it) {
    const int tbase = tw + it * 128;

    // prefetch next iter's A (latency hides under MFMA + epilogue)
    if (it < 7) {
      const u16* arow = s_bf + (size_t)(tbase + 128 + c) * 256 + g * 8;
#pragma unroll
      for (int ks = 0; ks < 8; ++ks) afn[ks] = *(const bf16x8*)(arow + ks * 32);
    }

    int a0 = actions[tbase + g * 4 + 0];
    int a1 = actions[tbase + g * 4 + 1];
    int a2 = actions[tbase + g * 4 + 2];
    int a3 = actions[tbase + g * 4 + 3];

    f32x4 acc[4];
#pragma unroll
    for (int nf = 0; nf < 4; ++nf) acc[nf] = (f32x4){0.f, 0.f, 0.f, 0.f};

#pragma unroll
    for (int ks = 0; ks < 8; ++ks)
#pragma unroll
      for (int nf = 0; nf < 4; ++nf)
        acc[nf] = __builtin_amdgcn_mfma_f32_16x16x32_bf16(af[ks], bq[ks][nf], acc[nf], 0, 0, 0);

    // epilogue: row g*4+q; no-max softmax over 64 cols (16 c-lanes x 4 nf)
    const int acts[4] = {a0, a1, a2, a3};
#pragma unroll
    for (int q = 0; q < 4; ++q) {
      float e0 = __expf(acc[0][q]);
      float e1 = __expf(acc[1][q]);
      float e2 = __expf(acc[2][q]);
      float e3 = __expf(acc[3][q]);
      float s = (e0 + e1) + (e2 + e3);
#pragma unroll
      for (int d = 1; d < 16; d <<= 1) s += __shfl_xor(s, d);
      int a = acts[q];
      int acf = a >> 4;
      float esel = (acf == 0) ? e0 : (acf == 1) ? e1 : (acf == 2) ? e2 : e3;
      if (c == (a & 15))
        peT[pebase + tbase + g * 4 + q] = esel / s;
    }

#pragma unroll
    for (int ks = 0; ks < 8; ++ks) af[ks] = afn[ks];
  }
}

// ---------------- start/stop GEMM + fused softmax/sigmoid ----------------
__global__ __launch_bounds__(256) void small_gemm(
    const u16* __restrict__ s_bf, const u16* __restrict__ wsm_t,
    float* __restrict__ ps, float* __restrict__ pb, float* __restrict__ pc) {
  __shared__ uint4 ldsA[64 * 16];
  __shared__ uint4 ldsB[192 * 16];
  const int t0 = blockIdx.x * 64;
  const int tid = threadIdx.x;
  const int lane = tid & 63, w = tid >> 6;
  const int g = lane >> 4, c = lane & 15;

  f32x4 acc[12];
#pragma unroll
  for (int i = 0; i < 12; ++i) acc[i] = (f32x4){0.f, 0.f, 0.f, 0.f};

  for (int kh = 0; kh < 2; ++kh) {
    if (kh) __syncthreads();
    for (int i = tid; i < 64 * 16; i += 256) {
      int row = i >> 4, u = i & 15;
      ldsA[(row * 16 + u) ^ (row & 7)] =
          *(const uint4*)(s_bf + (size_t)(t0 + row) * 256 + kh * 128 + u * 8);
    }
    for (int i = tid; i < 192 * 16; i += 256) {
      int row = i >> 4, u = i & 15;
      ldsB[(row * 16 + u) ^ (row & 7)] =
          *(const uint4*)(wsm_t + (size_t)row * 256 + kh * 128 + u * 8);
    }
    __syncthreads();
#pragma unroll
    for (int kk = 0; kk < 4; ++kk) {
      int u = kk * 4 + g;
      int arow = w * 16 + c;
      bf16x8 af = *(const bf16x8*)&ldsA[(arow * 16 + u) ^ (arow & 7)];
#pragma unroll
      for (int cf = 0; cf < 12; ++cf) {
        int brow = cf * 16 + c;
        bf16x8 bfr = *(const bf16x8*)&ldsB[(brow * 16 + u) ^ (brow & 7)];
        acc[cf] = __builtin_amdgcn_mfma_f32_16x16x32_bf16(af, bfr, acc[cf], 0, 0, 0);
      }
    }
  }

#pragma unroll
  for (int q = 0; q < 4; ++q) {
    int t = t0 + w * 16 + g * 4 + q;
    float v0 = acc[0][q], v1 = acc[1][q], v2 = acc[2][q], v3 = acc[3][q];
    float m = fmaxf(fmaxf(v0, v1), fmaxf(v2, v3));
#pragma unroll
    for (int d = 1; d < 16; d <<= 1) m = fmaxf(m, __shfl_xor(m, d));
    float s = __expf(v0 - m) + __expf(v1 - m) + __expf(v2 - m) + __expf(v3 - m);
#pragma unroll
    for (int d = 1; d < 16; d <<= 1) s += __shfl_xor(s, d);
    float lse = m + __logf(s);
    if (t <= T_LEN) {
      ps[t * 64 + 0 * 16 + c] = __expf(v0 - lse);
      ps[t * 64 + 1 * 16 + c] = __expf(v1 - lse);
      ps[t * 64 + 2 * 16 + c] = __expf(v2 - lse);
      ps[t * 64 + 3 * 16 + c] = __expf(v3 - lse);
#pragma unroll
      for (int bf = 0; bf < 4; ++bf) {
        float l0 = acc[4 + bf][q], l1 = acc[8 + bf][q];
        float d01 = l0 - l1;
        pb[t * 64 + bf * 16 + c] = 1.f / (1.f + __expf(-d01));
        pc[t * 64 + bf * 16 + c] = 1.f / (1.f + __expf(d01));
      }
    }
  }
}

// ---------------- chunked scan: 4 waves per chunk ----------------
__global__ __launch_bounds__(256) void chunk_kernel(
    const float* __restrict__ peT, const float* __restrict__ ps,
    const float* __restrict__ pb, const float* __restrict__ pc,
    float* __restrict__ Mout, float* __restrict__ lscale) {
  __shared__ float scal[64 * 196];   // per step: [b(64) | ec(64) | es(64) | pad]
  __shared__ float part[2][256];
  __shared__ float mxs[4];
  const int ck = blockIdx.x;
  const int tid = threadIdx.x;
  const int lane = tid & 63;
  const int w = tid >> 6;
  const int tlo = ck * 64 + 1;

#pragma unroll
  for (int it = 0; it < 16; ++it) {
    int i = tid + 256 * it;
    int st = i >> 6, j = i & 63;
    int t = tlo + st;
    if (t <= T_LEN - 1) {
      int base = t * 64 + j;
      scal[st * 196 + j]       = pb[base];
      scal[st * 196 + 64 + j]  = pc[base];
      scal[st * 196 + 128 + j] = ps[base];
    } else {
      scal[st * 196 + j]       = 0.f;
      scal[st * 196 + 64 + j]  = 1.f;
      scal[st * 196 + 128 + j] = 0.f;
    }
  }
  __syncthreads();
#pragma unroll
  for (int it = 0; it < 16; ++it) {
    int i = tid + 256 * it;
    int j = i >> 6, st = i & 63;
    int t = tlo + st;
    if (t <= T_LEN - 1) {
      float e = peT[(size_t)j * 8192 + t];
      scal[st * 196 + 64 + j]  *= e;
      scal[st * 196 + 128 + j] *= e;
    }
  }
  __syncthreads();

  float M[16];
#pragma unroll
  for (int jj = 0; jj < 16; ++jj) M[jj] = ((w * 16 + jj) == lane) ? 1.f : 0.f;
  float lsc = 0.f;
  int pbuf = 0;

  for (int st = 0; st < 64; ++st) {
    const float* sb = &scal[st * 196];
    float p0 = 0.f, p1 = 0.f, p2 = 0.f, p3 = 0.f;
#pragma unroll
    for (int q = 0; q < 4; ++q) {
      float4 bq = *(const float4*)(sb + w * 16 + q * 4);
      p0 = fmaf(bq.x, M[q * 4 + 0], p0);
      p1 = fmaf(bq.y, M[q * 4 + 1], p1);
      p2 = fmaf(bq.z, M[q * 4 + 2], p2);
      p3 = fmaf(bq.w, M[q * 4 + 3], p3);
    }
    part[pbuf][w * 64 + lane] = (p0 + p1) + (p2 + p3);
    __syncthreads();
    float wv = part[pbuf][lane] + part[pbuf][64 + lane] +
               part[pbuf][128 + lane] + part[pbuf][192 + lane];
    pbuf ^= 1;
#pragma unroll
    for (int q = 0; q < 4; ++q) {
      float4 ecq = *(const float4*)(sb + 64 + w * 16 + q * 4);
      float4 esq = *(const float4*)(sb + 128 + w * 16 + q * 4);
      M[q * 4 + 0] = fmaf(ecq.x, M[q * 4 + 0], esq.x * wv);
      M[q * 4 + 1] = fmaf(ecq.y, M[q * 4 + 1], esq.y * wv);
      M[q * 4 + 2] = fmaf(ecq.z, M[q * 4 + 2], esq.z * wv);
      M[q * 4 + 3] = fmaf(ecq.w, M[q * 4 + 3], esq.w * wv);
    }
    if ((st & 7) == 7) {
      float mx = M[0];
#pragma unroll
      for (int jj = 1; jj < 16; ++jj) mx = fmaxf(mx, M[jj]);
#pragma unroll
      for (int d = 1; d < 64; d <<= 1) mx = fmaxf(mx, __shfl_xor(mx, d));
      if (lane == 0) mxs[w] = mx;
      __syncthreads();
      float bm = fmaxf(fmaxf(mxs[0], mxs[1]), fmaxf(mxs[2], mxs[3]));
      float inv = 1.f / bm;
#pragma unroll
      for (int jj = 0; jj < 16; ++jj) M[jj] *= inv;
      lsc += __logf(bm);
    }
  }

  float* out = Mout + (size_t)ck * 4096;
#pragma unroll
  for (int q = 0; q < 4; ++q) {
    float4 v = make_float4(M[q * 4 + 0], M[q * 4 + 1], M[q * 4 + 2], M[q * 4 + 3]);
    *(float4*)(out + lane * 64 + w * 16 + q * 4) = v;
  }
  if (tid == 0) lscale[ck] = lsc;
}

// ---------------- level-1 combine: 16 groups x 8 chunk matrices ----------------
__global__ __launch_bounds__(256) void group_combine(
    const float* __restrict__ Mout, const float* __restrict__ lscale,
    float* __restrict__ Gout, float* __restrict__ glsc) {
  const int g = blockIdx.x;
  const int tid = threadIdx.x;
  const int j = tid & 63;
  const int w = tid >> 6;
  __shared__ float Xa[64 * 68];
  __shared__ float Xb[64 * 68];
  __shared__ float Ma[64 * 68];
  __shared__ float Mb[64 * 68];
  __shared__ float red[4];

  {
    const float* M0 = Mout + (size_t)(8 * g) * 4096;
    const float* M1 = Mout + (size_t)(8 * g + 1) * 4096;
    for (int idx = tid; idx < 4096; idx += 256) {
      int i = idx >> 6, r = idx & 63;
      Xa[r * 68 + i] = M0[idx];
      Ma[i * 68 + r] = M1[idx];
    }
  }
  __syncthreads();

  float lsc = 0.f;
  float* Xcur = Xa; float* Xnxt = Xb;
  float* Mcur = Ma; float* Mnxt = Mb;

  for (int m = 1; m < 8; ++m) {
    float4 pf[4];
    if (m < 7) {
      const float* Mn = Mout + (size_t)(8 * g + m + 1) * 4096;
#pragma unroll
      for (int ii = 0; ii < 4; ++ii)
        pf[ii] = *(const float4*)(Mn + tid * 4 + 1024 * ii);
    }

    float acc[16];
#pragma unroll
    for (int i = 0; i < 16; ++i) acc[i] = 0.f;

#pragma unroll 4
    for (int k = 0; k < 64; ++k) {
      float mv = Mcur[k * 68 + j];
      const float* xr = Xcur + k * 68 + (w << 4);
      float4 x0 = *(const float4*)(xr + 0);
      float4 x1 = *(const float4*)(xr + 4);
      float4 x2 = *(const float4*)(xr + 8);
      float4 x3 = *(const float4*)(xr + 12);
      acc[0]  = fmaf(mv, x0.x, acc[0]);  acc[1]  = fmaf(mv, x0.y, acc[1]);
      acc[2]  = fmaf(mv, x0.z, acc[2]);  acc[3]  = fmaf(mv, x0.w, acc[3]);
      acc[4]  = fmaf(mv, x1.x, acc[4]);  acc[5]  = fmaf(mv, x1.y, acc[5]);
      acc[6]  = fmaf(mv, x1.z, acc[6]);  acc[7]  = fmaf(mv, x1.w, acc[7]);
      acc[8]  = fmaf(mv, x2.x, acc[8]);  acc[9]  = fmaf(mv, x2.y, acc[9]);
      acc[10] = fmaf(mv, x2.z, acc[10]); acc[11] = fmaf(mv, x2.w, acc[11]);
      acc[12] = fmaf(mv, x3.x, acc[12]); acc[13] = fmaf(mv, x3.y, acc[13]);
      acc[14] = fmaf(mv, x3.z, acc[14]); acc[15] = fmaf(mv, x3.w, acc[15]);
    }

    float lm = acc[0];
#pragma unroll
    for (int i = 1; i < 16; ++i) lm = fmaxf(lm, acc[i]);
#pragma unroll
    for (int d = 1; d < 64; d <<= 1) lm = fmaxf(lm, __shfl_xor(lm, d));
    if ((tid & 63) == 0) red[w] = lm;
    __syncthreads();
    float bm = fmaxf(fmaxf(red[0], red[1]), fmaxf(red[2], red[3]));
    float inv = 1.f / bm;
    lsc += __logf(bm);
#pragma unroll
    for (int i = 0; i < 16; ++i)
      Xnxt[j * 68 + (w << 4) + i] = acc[i] * inv;
    if (m < 7) {
#pragma unroll
      for (int ii = 0; ii < 4; ++ii) {
        int idx = tid * 4 + 1024 * ii;
        int k = idx >> 6, jj = idx & 63;
        *(float4*)(Mnxt + k * 68 + jj) = pf[ii];
      }
    }
    __syncthreads();
    float* t = Xcur; Xcur = Xnxt; Xnxt = t;
    float* tm = Mcur; Mcur = Mnxt; Mnxt = tm;
  }

  float* out = Gout + (size_t)g * 4096;
  for (int idx = tid; idx < 4096; idx += 256) {
    int i = idx >> 6, r = idx & 63;
    out[idx] = Xcur[r * 68 + i];
  }
  if (tid == 0) {
    float s = lsc;
#pragma unroll
    for (int m = 0; m < 8; ++m) s += lscale[8 * g + m];
    glsc[g] = s;
  }
}

// ---------------- level-2 combine: 16 sequential mat-vecs ----------------
__global__ __launch_bounds__(256) void final_combine(
    const float* __restrict__ Gout, const float* __restrict__ glsc,
    const float* __restrict__ peT, const float* __restrict__ ps,
    const float* __restrict__ pb, float* __restrict__ out) {
  const int tid = threadIdx.x;
  const int j = tid & 63, w = tid >> 6;
  __shared__ float vsh[64];
  __shared__ float part[4 * 64];
  if (tid < 64) vsh[tid] = ps[tid] * peT[(size_t)tid * 8192];   // f0
  __syncthreads();
  double lsc = 0.0;
  for (int gph = 0; gph < 16; ++gph) {
    const float* Gc = Gout + (size_t)gph * 4096;
    const int k0 = w << 4;
    float a0 = 0.f, a1 = 0.f, a2 = 0.f, a3 = 0.f;
#pragma unroll
    for (int kk = 0; kk < 16; kk += 4) {
      a0 = fmaf(vsh[k0 + kk + 0], Gc[(k0 + kk + 0) * 64 + j], a0);
      a1 = fmaf(vsh[k0 + kk + 1], Gc[(k0 + kk + 1) * 64 + j], a1);
      a2 = fmaf(vsh[k0 + kk + 2], Gc[(k0 + kk + 2) * 64 + j], a2);
      a3 = fmaf(vsh[k0 + kk + 3], Gc[(k0 + kk + 3) * 64 + j], a3);
    }
    part[w * 64 + j] = (a0 + a1) + (a2 + a3);
    __syncthreads();
    if (w == 0) {
      float u = part[j] + part[64 + j] + part[128 + j] + part[192 + j];
      float mx = u;
#pragma unroll
      for (int d = 1; d < 64; d <<= 1) mx = fmaxf(mx, __shfl_xor(mx, d));
      vsh[j] = u / mx;
      lsc += (double)__logf(mx) + (double)glsc[gph];
    }
    __syncthreads();
  }
  if (w == 0) {
    float z = vsh[j] * pb[T_LEN * 64 + j];
#pragma unroll
    for (int d = 1; d < 64; d <<= 1) z += __shfl_xor(z, d);
    if (j == 0) out[0] = (float)(-((double)logf(z) + lsc));
  }
}

extern "C" void kernel_launch(void* const* d_in, const int* in_sizes, int n_in,
                              void* d_out, int out_size, void* d_ws, size_t ws_size,
                              hipStream_t stream) {
  const float* s_i      = (const float*)d_in[0];
  const float* W_action = (const float*)d_in[1];
  const float* W_stop   = (const float*)d_in[2];
  const float* W_start  = (const float*)d_in[3];
  const int*   actions  = (const int*)d_in[4];

  char* ws = (char*)d_ws;
  u16*   s_bf  = (u16*)(ws + WS_SBF);
  u16*   wa_t  = (u16*)(ws + WS_WAT);
  u16*   wsm_t = (u16*)(ws + WS_WSMT);
  float* peT   = (float*)(ws + WS_PE);
  float* ps    = (float*)(ws + WS_PS);
  float* pb    = (float*)(ws + WS_PB);
  float* pc    = (float*)(ws + WS_PC);
  float* Mout  = (float*)(ws + WS_MOUT);
  float* lsc   = (float*)(ws + WS_LSC);
  float* Gout  = (float*)(ws + WS_GOUT);
  float* glsc  = (float*)(ws + WS_GLSC);

  conv_s<<<8256, 256, 0, stream>>>(s_i, s_bf);
  conv_wa<<<4096, 256, 0, stream>>>(W_action, wa_t);
  conv_wsm<<<192, 256, 0, stream>>>(W_stop, W_start, wsm_t);
  small_gemm<<<129, 256, 0, stream>>>(s_bf, wsm_t, ps, pb, pc);
  act_gemm<<<512, 512, 0, stream>>>(s_bf, wa_t, actions, peT);
  chunk_kernel<<<128, 256, 0, stream>>>(peT, ps, pb, pc, Mout, lsc);
  group_combine<<<16, 256, 0, stream>>>(Mout, lsc, Gout, glsc);
  final_combine<<<1, 256, 0, stream>>>(Gout, glsc, peT, ps, pb, (float*)d_out);
}